// Round 1
// baseline (374.065 us; speedup 1.0000x reference)
//
#include <hip/hip_runtime.h>
#include <cstdint>

#define B_ 16
#define A_ 32768
#define G_ 100

constexpr int APB = 2048;        // anchors per block in match kernel
constexpr int K_  = APB / 256;   // 8 anchors per thread

// ---------------------------------------------------------------------------
// Kernel 1: per-anchor best-over-g (first-g-wins) and per-g best-over-anchor
// (min-anchor-index tie-break) via packed u64 atomicMax.
// ---------------------------------------------------------------------------
__global__ __launch_bounds__(256) void k_match(
    const float* __restrict__ anchors,          // [B,A,2]
    const float* __restrict__ targets,          // [B,G,3]
    unsigned long long* __restrict__ keys,      // [B,G]  (zeroed)
    float* __restrict__ bto,                    // [B,A]
    int* __restrict__ bti)                      // [B,A]
{
    __shared__ float sg0[G_], sg1[G_], slg[G_];
    __shared__ int   sva[G_];

    const int b     = blockIdx.y;
    const int chunk = blockIdx.x;
    const int tid   = threadIdx.x;

    if (tid < G_) {
        float t0 = targets[(b * G_ + tid) * 3 + 0];
        float t1 = targets[(b * G_ + tid) * 3 + 1];
        float lb = targets[(b * G_ + tid) * 3 + 2];
        sg0[tid] = t0;
        sg1[tid] = t1;
        slg[tid] = t1 - t0;
        sva[tid] = (lb > 0.0f) ? 1 : 0;
    }
    __syncthreads();

    const int base = chunk * APB;

    float a0[K_], a1[K_], la[K_];
#pragma unroll
    for (int k = 0; k < K_; ++k) {
        int a = base + tid + k * 256;
        float2 v = ((const float2*)anchors)[b * A_ + a];
        a0[k] = v.x;
        a1[k] = v.y;
        la[k] = v.y - v.x;
    }

    float bestV[K_];
    int   bestG[K_];
#pragma unroll
    for (int k = 0; k < K_; ++k) { bestV[k] = -2.0f; bestG[k] = 0; }

    for (int g = 0; g < G_; ++g) {
        const float g0 = sg0[g], g1 = sg1[g], lg = slg[g];
        const int valid = sva[g];

        float    gBest = -1.0f;   // iou >= 0 always, so any anchor beats init
        unsigned gIdx  = 0;

#pragma unroll
        for (int k = 0; k < K_; ++k) {
            float inter = fminf(g1, a1[k]) - fmaxf(g0, a0[k]);
            inter = fmaxf(inter, 0.0f);
            float iou = inter / (lg + la[k] - inter);   // IEEE div, matches ref
            float val = valid ? iou : -1.0f;
            if (val > bestV[k]) { bestV[k] = val; bestG[k] = g; }   // first-g-wins
            if (iou > gBest) {                                      // first-anchor-wins (ascending k)
                gBest = iou;
                gIdx  = (unsigned)(base + tid + k * 256);
            }
        }

        if (valid) {
            // pack: high = iou bits (iou>=0 so monotone), low = ~anchor_idx
            unsigned long long key =
                ((unsigned long long)__float_as_uint(gBest) << 32) |
                (unsigned long long)(0xFFFFFFFFu - gIdx);
#pragma unroll
            for (int off = 32; off > 0; off >>= 1) {
                unsigned long long o = __shfl_xor(key, off, 64);
                if (o > key) key = o;
            }
            if ((tid & 63) == 0) atomicMax(&keys[b * G_ + g], key);
        }
    }

#pragma unroll
    for (int k = 0; k < K_; ++k) {
        int a = base + tid + k * 256;
        bto[b * A_ + a] = bestV[k];
        bti[b * A_ + a] = bestG[k];
    }
}

// ---------------------------------------------------------------------------
// Kernel 2: scatter best-prior assignments (serial ascending g -> last-g-wins
// on duplicate anchors, matching XLA/CPU scatter update order).
// ---------------------------------------------------------------------------
__global__ void k_scatter(
    const float* __restrict__ targets,
    const unsigned long long* __restrict__ keys,
    float* __restrict__ bto,
    int* __restrict__ bti)
{
    int b = threadIdx.x;
    if (b >= B_) return;
    for (int g = 0; g < G_; ++g) {
        float lb = targets[(b * G_ + g) * 3 + 2];
        if (lb > 0.0f) {
            unsigned aidx = 0xFFFFFFFFu -
                (unsigned)(keys[b * G_ + g] & 0xFFFFFFFFull);
            bto[b * A_ + aidx] = 2.0f;
            bti[b * A_ + aidx] = g;
        }
    }
}

// ---------------------------------------------------------------------------
// Kernel 3: per-anchor smooth-L1 on positives, block-reduced atomicAdd.
// ---------------------------------------------------------------------------
__global__ __launch_bounds__(256) void k_loss(
    const float* __restrict__ loc_pred,   // [B,A,2]
    const float* __restrict__ anchors,    // [B,A,2]
    const int*   __restrict__ ignore,     // [B,A]
    const float* __restrict__ targets,    // [B,G,3]
    const float* __restrict__ bto,
    const int*   __restrict__ bti,
    float* __restrict__ accum)            // [2]: sum, count (zeroed)
{
    const int i = blockIdx.x * 256 + threadIdx.x;   // global (b,a) index
    const int b = i / A_;

    float mysum = 0.0f, mycnt = 0.0f;

    float ov  = bto[i];
    int   g   = bti[i];
    int   ign = ignore[i];
    float lb  = targets[(b * G_ + g) * 3 + 2];

    bool pos = (ign == 0) && !(ov < 0.5f) && (lb > 0.0f);
    if (pos) {
        float m0 = targets[(b * G_ + g) * 3 + 0];
        float m1 = targets[(b * G_ + g) * 3 + 1];
        float2 av = ((const float2*)anchors)[i];
        float ac  = (av.x + av.y) * 0.5f;
        float asz = av.y - av.x;
        float gc  = (m0 + m1) * 0.5f;
        float gsz = m1 - m0;
        float lt0 = (gc - ac) / (0.1f * asz);
        float lt1 = logf(gsz / asz) / 0.2f;

        float2 lp = ((const float2*)loc_pred)[i];
        float d0 = lp.x - lt0, d1 = lp.y - lt1;
        float ad0 = fabsf(d0), ad1 = fabsf(d1);
        mysum = (ad0 < 1.0f ? 0.5f * d0 * d0 : ad0 - 0.5f) +
                (ad1 < 1.0f ? 0.5f * d1 * d1 : ad1 - 0.5f);
        mycnt = 1.0f;
    }

#pragma unroll
    for (int off = 32; off > 0; off >>= 1) {
        mysum += __shfl_down(mysum, off, 64);
        mycnt += __shfl_down(mycnt, off, 64);
    }
    __shared__ float ssum[4], scnt[4];
    int wid = threadIdx.x >> 6, lane = threadIdx.x & 63;
    if (lane == 0) { ssum[wid] = mysum; scnt[wid] = mycnt; }
    __syncthreads();
    if (threadIdx.x == 0) {
        float s = ssum[0] + ssum[1] + ssum[2] + ssum[3];
        float c = scnt[0] + scnt[1] + scnt[2] + scnt[3];
        if (s != 0.0f || c != 0.0f) {
            atomicAdd(&accum[0], s);
            atomicAdd(&accum[1], c);
        }
    }
}

__global__ void k_final(const float* __restrict__ accum, float* __restrict__ out)
{
    out[0] = accum[0] / accum[1];
}

// ---------------------------------------------------------------------------
extern "C" void kernel_launch(void* const* d_in, const int* in_sizes, int n_in,
                              void* d_out, int out_size, void* d_ws, size_t ws_size,
                              hipStream_t stream) {
    const float* loc_pred = (const float*)d_in[0];
    // d_in[1] = conf_pred : unused by the loss
    const float* anchors  = (const float*)d_in[2];
    const int*   ignore   = (const int*)d_in[3];
    const float* targets  = (const float*)d_in[4];
    float*       out      = (float*)d_out;

    char* ws = (char*)d_ws;
    unsigned long long* keys = (unsigned long long*)ws;        // B*G u64 = 12800 B
    float* accum = (float*)(ws + 12800);                       // 2 floats
    float* bto   = (float*)(ws + 16384);                       // B*A f32 = 2 MB
    int*   bti   = (int*)(ws + 16384 + (size_t)B_ * A_ * 4);   // B*A i32 = 2 MB

    hipMemsetAsync(ws, 0, 16384, stream);

    dim3 g1(A_ / APB, B_);
    k_match<<<g1, 256, 0, stream>>>(anchors, targets, keys, bto, bti);
    k_scatter<<<1, 64, 0, stream>>>(targets, keys, bto, bti);
    k_loss<<<(B_ * A_) / 256, 256, 0, stream>>>(loc_pred, anchors, ignore,
                                                targets, bto, bti, accum);
    k_final<<<1, 1, 0, stream>>>(accum, out);
}

// Round 10
// 311.884 us; speedup vs baseline: 1.1994x; 1.1994x over previous
//
#include <hip/hip_runtime.h>
#include <cstdint>

#define B_ 16
#define A_ 32768
#define G_ 100

constexpr int APBG = 512;          // anchors per block in k_best_g
constexpr int KG   = APBG / 256;   // 2 anchors per thread

// ---------------------------------------------------------------------------
// Kernel 1: per-anchor argmax over g (first-valid-g-wins), rcp-approx compares,
// exact IEEE division only for the final stored overlap value.
// ---------------------------------------------------------------------------
__global__ __launch_bounds__(256) void k_best_g(
    const float* __restrict__ anchors,   // [B,A,2]
    const float* __restrict__ targets,   // [B,G,3]
    float* __restrict__ bto,             // [B,A]
    int* __restrict__ bti)               // [B,A]
{
    __shared__ float4 sg[G_];            // (g0, g1, len_g, label)

    const int b   = blockIdx.y;
    const int tid = threadIdx.x;

    if (tid < G_) {
        float t0 = targets[(b * G_ + tid) * 3 + 0];
        float t1 = targets[(b * G_ + tid) * 3 + 1];
        float lb = targets[(b * G_ + tid) * 3 + 2];
        sg[tid] = make_float4(t0, t1, t1 - t0, lb);
    }
    __syncthreads();

    const int base = blockIdx.x * APBG;

    float a0[KG], a1[KG], la[KG], bi[KG], bu[KG], bv[KG];
    int   bg[KG];
#pragma unroll
    for (int k = 0; k < KG; ++k) {
        float2 v = ((const float2*)anchors)[b * A_ + base + tid + k * 256];
        a0[k] = v.x; a1[k] = v.y; la[k] = v.y - v.x;
        bi[k] = -1.0f; bu[k] = 1.0f; bv[k] = -1.0f; bg[k] = 0;
    }

    for (int g = 0; g < G_; ++g) {
        float4 t = sg[g];
        if (!(t.w > 0.0f)) continue;     // invalid g: ref value -1, never wins
#pragma unroll
        for (int k = 0; k < KG; ++k) {
            float inter = fmaxf(fminf(t.y, a1[k]) - fmaxf(t.x, a0[k]), 0.0f);
            float u     = (t.z + la[k]) - inter;
            float iou   = inter * __builtin_amdgcn_rcpf(u);
            if (iou > bv[k]) { bv[k] = iou; bi[k] = inter; bu[k] = u; bg[k] = g; }
        }
    }

#pragma unroll
    for (int k = 0; k < KG; ++k) {
        int a = base + tid + k * 256;
        bto[b * A_ + a] = bi[k] / bu[k];   // exact IEEE div of selected pair
        bti[b * A_ + a] = bg[k];
    }
}

// ---------------------------------------------------------------------------
// Kernel 2: per-g argmax over anchors. One block per (b,g); block-level
// reduce; one atomicMax(forced, g) -> last(=max)-g-wins, matching the serial
// ascending-g scatter semantics of the reference.
// ---------------------------------------------------------------------------
__global__ __launch_bounds__(256) void k_best_a(
    const float* __restrict__ anchors,
    const float* __restrict__ targets,
    int* __restrict__ forced)            // [B,A], pre-set to -1
{
    const int g = blockIdx.x, b = blockIdx.y, tid = threadIdx.x;

    float t0 = targets[(b * G_ + g) * 3 + 0];
    float t1 = targets[(b * G_ + g) * 3 + 1];
    float lb = targets[(b * G_ + g) * 3 + 2];
    if (!(lb > 0.0f)) return;            // invalid g: dropped by ref scatter
    float lg = t1 - t0;

    float    bestV = -1.0f;
    unsigned bestA = 0;
    const float2* ap = (const float2*)anchors + b * A_;

#pragma unroll 4
    for (int j = 0; j < A_ / 256; ++j) {
        int a = tid + j * 256;
        float2 v = ap[a];
        float la    = v.y - v.x;
        float inter = fmaxf(fminf(t1, v.y) - fmaxf(t0, v.x), 0.0f);
        float u     = (lg + la) - inter;
        float iou   = inter * __builtin_amdgcn_rcpf(u);
        if (iou > bestV) { bestV = iou; bestA = (unsigned)a; }  // first-wins
    }

    // pack: high = iou bits (>=0 so monotone), low = ~idx (min-idx tie-break)
    unsigned long long key =
        ((unsigned long long)__float_as_uint(bestV) << 32) |
        (unsigned long long)(0xFFFFFFFFu - bestA);
#pragma unroll
    for (int off = 32; off > 0; off >>= 1) {
        unsigned long long o = __shfl_xor(key, off, 64);
        if (o > key) key = o;
    }
    __shared__ unsigned long long sk[4];
    if ((tid & 63) == 0) sk[tid >> 6] = key;
    __syncthreads();
    if (tid == 0) {
        unsigned long long k0 = sk[0];
#pragma unroll
        for (int w = 1; w < 4; ++w) if (sk[w] > k0) k0 = sk[w];
        unsigned aidx = 0xFFFFFFFFu - (unsigned)(k0 & 0xFFFFFFFFull);
        atomicMax(&forced[b * A_ + aidx], g);
    }
}

// ---------------------------------------------------------------------------
// Kernel 3: per-anchor smooth-L1 on positives, block-reduced atomicAdd.
// ---------------------------------------------------------------------------
__global__ __launch_bounds__(256) void k_loss(
    const float* __restrict__ loc_pred,
    const float* __restrict__ anchors,
    const int*   __restrict__ ignore,
    const float* __restrict__ targets,
    const float* __restrict__ bto,
    const int*   __restrict__ bti,
    const int*   __restrict__ forced,
    float* __restrict__ accum)           // [2]: sum, count (zeroed)
{
    const int i = blockIdx.x * 256 + threadIdx.x;
    const int b = i >> 15;               // A_ = 32768

    float ov = bto[i];
    int   g  = bti[i];
    int   f  = forced[i];
    if (f >= 0) { g = f; ov = 2.0f; }    // scatter override, last-g-wins
    int   ign = ignore[i];
    float lb  = targets[(b * G_ + g) * 3 + 2];

    float mysum = 0.0f, mycnt = 0.0f;
    bool pos = (ign == 0) && (ov >= 0.5f) && (lb > 0.0f);
    if (pos) {
        float m0 = targets[(b * G_ + g) * 3 + 0];
        float m1 = targets[(b * G_ + g) * 3 + 1];
        float2 av = ((const float2*)anchors)[i];
        float ac  = (av.x + av.y) * 0.5f;
        float asz = av.y - av.x;
        float gc  = (m0 + m1) * 0.5f;
        float gsz = m1 - m0;
        float lt0 = (gc - ac) / (0.1f * asz);
        float lt1 = logf(gsz / asz) / 0.2f;

        float2 lp = ((const float2*)loc_pred)[i];
        float d0 = lp.x - lt0, d1 = lp.y - lt1;
        float ad0 = fabsf(d0), ad1 = fabsf(d1);
        mysum = (ad0 < 1.0f ? 0.5f * d0 * d0 : ad0 - 0.5f) +
                (ad1 < 1.0f ? 0.5f * d1 * d1 : ad1 - 0.5f);
        mycnt = 1.0f;
    }

#pragma unroll
    for (int off = 32; off > 0; off >>= 1) {
        mysum += __shfl_down(mysum, off, 64);
        mycnt += __shfl_down(mycnt, off, 64);
    }
    __shared__ float ssum[4], scnt[4];
    int wid = threadIdx.x >> 6, lane = threadIdx.x & 63;
    if (lane == 0) { ssum[wid] = mysum; scnt[wid] = mycnt; }
    __syncthreads();
    if (threadIdx.x == 0) {
        float s = ssum[0] + ssum[1] + ssum[2] + ssum[3];
        float c = scnt[0] + scnt[1] + scnt[2] + scnt[3];
        if (s != 0.0f || c != 0.0f) {
            atomicAdd(&accum[0], s);
            atomicAdd(&accum[1], c);
        }
    }
}

__global__ void k_final(const float* __restrict__ accum, float* __restrict__ out)
{
    out[0] = accum[0] / accum[1];
}

// ---------------------------------------------------------------------------
extern "C" void kernel_launch(void* const* d_in, const int* in_sizes, int n_in,
                              void* d_out, int out_size, void* d_ws, size_t ws_size,
                              hipStream_t stream) {
    const float* loc_pred = (const float*)d_in[0];
    // d_in[1] = conf_pred : unused by the loss
    const float* anchors  = (const float*)d_in[2];
    const int*   ignore   = (const int*)d_in[3];
    const float* targets  = (const float*)d_in[4];
    float*       out      = (float*)d_out;

    char* ws = (char*)d_ws;
    float* accum  = (float*)ws;                                   // 8 B
    int*   forced = (int*)(ws + 4096);                            // B*A i32 = 2 MB
    float* bto    = (float*)(ws + 4096 + (size_t)B_ * A_ * 4);    // 2 MB
    int*   bti    = (int*)(ws + 4096 + (size_t)B_ * A_ * 8);      // 2 MB

    hipMemsetAsync(accum, 0, 16, stream);
    hipMemsetAsync(forced, 0xFF, (size_t)B_ * A_ * 4, stream);    // -1

    dim3 gg(A_ / APBG, B_);
    k_best_g<<<gg, 256, 0, stream>>>(anchors, targets, bto, bti);
    dim3 ga(G_, B_);
    k_best_a<<<ga, 256, 0, stream>>>(anchors, targets, forced);
    k_loss<<<(B_ * A_) / 256, 256, 0, stream>>>(loc_pred, anchors, ignore,
                                                targets, bto, bti, forced, accum);
    k_final<<<1, 1, 0, stream>>>(accum, out);
}